// Round 13
// baseline (433.714 us; speedup 1.0000x reference)
//
#include <hip/hip_runtime.h>
#include <hip/hip_bf16.h>

// Fused triplane sample + reshape-semantics MLP (32->128->128->4, ReLU),
// FP32 out, perm [1,2,3,0] baked into w2/b2.
// r10 structure (proven 244us) + phase-B register diet: weight fragments are
// loaded from global (L1-hot) at use instead of register-cached, cutting
// ~160 VGPRs so blocks/CU can exceed 1 (occupancy was pinned at 1 block/CU).

#define C_ 32
#define HW_ (128 * 128)
#define HBS 136               /* per-wave transpose buf row stride (bf16) */

typedef short s8v __attribute__((ext_vector_type(8)));
typedef float f4v __attribute__((ext_vector_type(4)));
typedef unsigned int u4v __attribute__((ext_vector_type(4)));

__device__ __attribute__((aligned(64))) unsigned short g_planes[3 * HW_ * C_]; // (3,H,W,C) bf16
__device__ __attribute__((aligned(16))) unsigned short g_w0[128 * 32];
__device__ __attribute__((aligned(16))) unsigned short g_w1[128 * 128];
__device__ __attribute__((aligned(16))) unsigned short g_w2[16 * 128];  // perm-baked, padded
__device__ float g_b0[128];
__device__ float g_b1[128];
__device__ float g_b2p[16];

template <typename TO, typename FROM>
static __device__ __forceinline__ TO bitc(FROM f) {
    union { FROM a; TO b; } u; u.a = f; return u.b;
}

// MFMA operand-type shim (v8i16 vs v8bf16 builtin signature) -- proven.
template <typename V>
static __device__ __forceinline__ auto mfma_k32(V a, V b, f4v c, int)
    -> decltype(__builtin_amdgcn_mfma_f32_16x16x32_bf16(a, b, c, 0, 0, 0)) {
    return __builtin_amdgcn_mfma_f32_16x16x32_bf16(a, b, c, 0, 0, 0);
}
template <typename V>
static __device__ __forceinline__ f4v mfma_k32(V a, V b, f4v c, long) {
    typedef __bf16 b8v __attribute__((ext_vector_type(8)));
    return __builtin_amdgcn_mfma_f32_16x16x32_bf16(bitc<b8v>(a), bitc<b8v>(b), c, 0, 0, 0);
}
static __device__ __forceinline__ f4v MFMA(s8v a, s8v b, f4v c) {
    return mfma_k32(a, b, c, 0);
}

__device__ __forceinline__ unsigned short f2bf(float f) {
    union { float f; unsigned int i; } v; v.f = f;
    unsigned int r = v.i + 0x7FFFu + ((v.i >> 16) & 1u);
    return (unsigned short)(r >> 16);
}

// ---- prep: planes (3C,H,W) fp32 -> (3,H,W,C) bf16 ---------------------------
__global__ void prep_planes_k(const float* __restrict__ tp) {
    int o = blockIdx.x * 256 + threadIdx.x;   // 1572864 threads
    if (o >= 3 * HW_ * C_) return;
    int c  = o & 31;
    int xy = (o >> 5) & (HW_ - 1);
    int pl = o >> 19;
    g_planes[o] = f2bf(tp[(pl * C_ + c) * HW_ + xy]);
}

// ---- prep: weights/biases -> bf16; w2/b2 permuted [1,2,3,0], padded ---------
__global__ void prep_weights_k(const float* __restrict__ w0, const float* __restrict__ b0,
                               const float* __restrict__ w1, const float* __restrict__ b1,
                               const float* __restrict__ w2, const float* __restrict__ b2) {
    int i = blockIdx.x * 256 + threadIdx.x;   // 16384 threads
    if (i < 128 * 32)  g_w0[i] = f2bf(w0[i]);
    if (i < 128 * 128) g_w1[i] = f2bf(w1[i]);
    if (i < 16 * 128) {
        int n = i >> 7, k = i & 127;
        g_w2[i] = f2bf(n < 4 ? w2[((n + 1) & 3) * 128 + k] : 0.0f);
    }
    if (i < 128) { g_b0[i] = b0[i]; g_b1[i] = b1[i]; }
    if (i < 16)  g_b2p[i] = (i < 4) ? b2[(i + 1) & 3] : 0.0f;
}

// ---- bilinear sample: all 32 channels via 16B vector loads ------------------
__device__ __forceinline__ void sample_plane32(const unsigned short* __restrict__ pbase,
                                               float u, float v, float* facc) {
    float x = (u + 1.0f) * 63.5f;             // align_corners=True, W=H=128
    float y = (v + 1.0f) * 63.5f;
    float xf = floorf(x), yf = floorf(y);
    float wx = x - xf, wy = y - yf;
    int x0 = (int)xf, y0 = (int)yf;
#pragma unroll
    for (int dy = 0; dy < 2; ++dy) {
        int yi = y0 + dy;
        float wyv = dy ? wy : 1.0f - wy;
        bool vy = (yi >= 0) && (yi < 128);
        int yc = yi < 0 ? 0 : (yi > 127 ? 127 : yi);
#pragma unroll
        for (int dx = 0; dx < 2; ++dx) {
            int xi = x0 + dx;
            float wv = (dx ? wx : 1.0f - wx) * wyv;
            bool vx = (xi >= 0) && (xi < 128);
            int xc = xi < 0 ? 0 : (xi > 127 ? 127 : xi);
            wv = (vx && vy) ? wv : 0.0f;
            const u4v* cp = (const u4v*)(pbase + (yc * 128 + xc) * C_);
#pragma unroll
            for (int q = 0; q < 4; ++q) {
                u4v dw = cp[q];
#pragma unroll
                for (int jj = 0; jj < 4; ++jj) {
                    facc[q * 8 + 2 * jj]     += wv * __uint_as_float(dw[jj] << 16);
                    facc[q * 8 + 2 * jj + 1] += wv * __uint_as_float(dw[jj] & 0xFFFF0000u);
                }
            }
        }
    }
}

// ---- fused kernel -----------------------------------------------------------
__global__ __launch_bounds__(256) void fused_k(const float* __restrict__ coords,
                                               float* __restrict__ out) {
    // S[32][512] bf16 = 32768 B, then 4 per-wave transpose bufs 16*HBS bf16.
    __shared__ __attribute__((aligned(16))) unsigned short smem[16384 + 4 * 16 * HBS];
    const int tid  = threadIdx.x;             // 0..255
    const int wave = tid >> 6;                // 0..3
    const int lane = tid & 63;
    const int l15  = lane & 15;
    const int quad = lane >> 4;
    const int ch8  = quad * 8;

    const int wg = blockIdx.x;                // 0..2047
    const int b  = wg >> 9;                   // batch
    const int nb = wg & 511;                  // 512-point block within batch
    const int n0 = nb << 9;

    // ---- phase A: sample 2 points/thread, all 32 channels -> S --------------
#pragma unroll 1
    for (int pt = 0; pt < 2; ++pt) {
        const int nl = tid + pt * 256;        // n_local 0..511
        const float* cp = coords + (size_t)(b * 262144 + n0 + nl) * 3;
        const float gx = cp[0], gy = cp[1], gz = cp[2];
        float facc[32];
#pragma unroll
        for (int c = 0; c < 32; ++c) facc[c] = 0.0f;
        sample_plane32(g_planes + 0 * (HW_ * C_), gx, gy, facc);  // feat_xy
        sample_plane32(g_planes + 2 * (HW_ * C_), gx, gz, facc);  // feat_xz
        sample_plane32(g_planes + 1 * (HW_ * C_), gy, gz, facc);  // feat_yz
#pragma unroll
        for (int c = 0; c < 32; ++c)
            smem[c * 512 + nl] = f2bf(facc[c]);
    }
    __syncthreads();

    // ---- small register-resident state (w2 fragments + biases only) ---------
    s8v w2f[4];
#pragma unroll
    for (int kc = 0; kc < 4; ++kc)
        w2f[kc] = *(const s8v*)(g_w2 + l15 * 128 + kc * 32 + ch8);
    float bias0[8], bias1[8];
#pragma unroll
    for (int nt = 0; nt < 8; ++nt) {
        bias0[nt] = g_b0[nt * 16 + l15];
        bias1[nt] = g_b1[nt * 16 + l15];
    }
    const float bias2 = g_b2p[l15];

    unsigned short* hb = smem + 16384 + wave * (16 * HBS);  // per-wave private
    float* hbf = (float*)hb;

    // ---- phase B: 8 channel-tiles per wave ----------------------------------
#pragma unroll 1
    for (int i = 0; i < 8; ++i) {
        const int ci = wave * 8 + i;          // channel 0..31
        // A fragment: A[m=l15][k=quad*8+j] = S[ci][l15*32 + ch8 + j]
        const s8v a = *(const s8v*)(smem + ci * 512 + l15 * 32 + ch8);

        // layer 1: weight fragment loaded at use (g_w0 is 8KB, L1-hot)
#pragma unroll
        for (int nt = 0; nt < 8; ++nt) {
            const s8v w0f = *(const s8v*)(g_w0 + (nt * 16 + l15) * 32 + ch8);
            f4v bi;
            bi[0] = bias0[nt]; bi[1] = bias0[nt]; bi[2] = bias0[nt]; bi[3] = bias0[nt];
            f4v c1 = MFMA(a, w0f, bi);
#pragma unroll
            for (int r = 0; r < 4; ++r) {
                float v = c1[r];
                hb[(quad * 4 + r) * HBS + nt * 16 + l15] = f2bf(v > 0.0f ? v : 0.0f);
            }
        }
        __builtin_amdgcn_s_waitcnt(0);
        s8v a2[4];
#pragma unroll
        for (int kc = 0; kc < 4; ++kc)
            a2[kc] = *(const s8v*)(hb + l15 * HBS + kc * 32 + ch8);

        // layer 2 in two nt-halves; w1 fragments loaded at use (32KB, L1-hot)
#pragma unroll
        for (int half = 0; half < 2; ++half) {
            f4v d[4];
#pragma unroll
            for (int j = 0; j < 4; ++j) {
                float bv = bias1[half * 4 + j];
                d[j][0] = bv; d[j][1] = bv; d[j][2] = bv; d[j][3] = bv;
            }
#pragma unroll
            for (int kc = 0; kc < 4; ++kc) {
#pragma unroll
                for (int j = 0; j < 4; ++j) {
                    const s8v w1f = *(const s8v*)(g_w1 +
                        ((half * 4 + j) * 16 + l15) * 128 + kc * 32 + ch8);
                    d[j] = MFMA(a2[kc], w1f, d[j]);
                }
            }
#pragma unroll
            for (int j = 0; j < 4; ++j)
#pragma unroll
                for (int r = 0; r < 4; ++r) {
                    float v = d[j][r];
                    hb[(quad * 4 + r) * HBS + (half * 4 + j) * 16 + l15] =
                        f2bf(v > 0.0f ? v : 0.0f);
                }
        }
        __builtin_amdgcn_s_waitcnt(0);
#pragma unroll
        for (int kc = 0; kc < 4; ++kc)        // reuse a2 as the layer-3 A frag
            a2[kc] = *(const s8v*)(hb + l15 * HBS + kc * 32 + ch8);

        // layer 3 -> relu
        f4v o;
        o[0] = bias2; o[1] = bias2; o[2] = bias2; o[3] = bias2;
#pragma unroll
        for (int kc = 0; kc < 4; ++kc)
            o = MFMA(a2[kc], w2f[kc], o);

        // transpose 16x4 through LDS -> one coalesced 256B store per tile
        if (l15 < 4) {
#pragma unroll
            for (int r = 0; r < 4; ++r) {
                float v = o[r];
                hbf[(quad * 4 + r) * 4 + l15] = v > 0.0f ? v : 0.0f;
            }
        }
        __builtin_amdgcn_s_waitcnt(0);
        const int t = b * 16384 + ci * 512 + nb;   // global tile index
        if (lane < 16) {
            f4v row = *(const f4v*)(hbf + lane * 4);
            *(f4v*)(out + (size_t)(t * 16 + lane) * 4) = row;
        }
        __builtin_amdgcn_s_waitcnt(0);        // hbf reads done before next tile
    }
}

extern "C" void kernel_launch(void* const* d_in, const int* in_sizes, int n_in,
                              void* d_out, int out_size, void* d_ws, size_t ws_size,
                              hipStream_t stream) {
    const float* coords = (const float*)d_in[0];
    const float* tp = (const float*)d_in[1];
    const float* w0 = (const float*)d_in[2];
    const float* b0 = (const float*)d_in[3];
    const float* w1 = (const float*)d_in[4];
    const float* b1 = (const float*)d_in[5];
    const float* w2 = (const float*)d_in[6];
    const float* b2 = (const float*)d_in[7];
    float* out = (float*)d_out;               // FP32 output

    prep_planes_k<<<6144, 256, 0, stream>>>(tp);
    prep_weights_k<<<64, 256, 0, stream>>>(w0, b0, w1, b1, w2, b2);
    fused_k<<<2048, 256, 0, stream>>>(coords, out);
}

// Round 14
// 322.587 us; speedup vs baseline: 1.3445x; 1.3445x over previous
//
#include <hip/hip_runtime.h>
#include <hip/hip_bf16.h>

// Fused triplane sample + reshape-semantics MLP (32->128->128->4, ReLU),
// FP32 out, perm [1,2,3,0] baked into w2/b2.
// r10 structure + occupancy fix: weights live in LDS in fragment-ready layout
// (sequential per-lane 16B ds_read_b128), A-fragments prefetched to registers,
// hb transpose buffers overlay the dead S region. ~72KB LDS -> 2 blocks/CU,
// register total stays low (no 160-reg weight cache -> was capping at 1 blk/CU).

#define C_ 32
#define HW_ (128 * 128)
#define HBS 136               /* per-wave transpose buf row stride (bf16) */

typedef short s8v __attribute__((ext_vector_type(8)));
typedef float f4v __attribute__((ext_vector_type(4)));
typedef unsigned int u4v __attribute__((ext_vector_type(4)));

__device__ __attribute__((aligned(64))) unsigned short g_planes[3 * HW_ * C_]; // (3,H,W,C) bf16
__device__ __attribute__((aligned(16))) unsigned short g_w0[128 * 32];
__device__ __attribute__((aligned(16))) unsigned short g_w1[128 * 128];
__device__ __attribute__((aligned(16))) unsigned short g_w2[16 * 128];  // perm-baked, padded
__device__ float g_b0[128];
__device__ float g_b1[128];
__device__ float g_b2p[16];

template <typename TO, typename FROM>
static __device__ __forceinline__ TO bitc(FROM f) {
    union { FROM a; TO b; } u; u.a = f; return u.b;
}

// MFMA operand-type shim (v8i16 vs v8bf16 builtin signature) -- proven.
template <typename V>
static __device__ __forceinline__ auto mfma_k32(V a, V b, f4v c, int)
    -> decltype(__builtin_amdgcn_mfma_f32_16x16x32_bf16(a, b, c, 0, 0, 0)) {
    return __builtin_amdgcn_mfma_f32_16x16x32_bf16(a, b, c, 0, 0, 0);
}
template <typename V>
static __device__ __forceinline__ f4v mfma_k32(V a, V b, f4v c, long) {
    typedef __bf16 b8v __attribute__((ext_vector_type(8)));
    return __builtin_amdgcn_mfma_f32_16x16x32_bf16(bitc<b8v>(a), bitc<b8v>(b), c, 0, 0, 0);
}
static __device__ __forceinline__ f4v MFMA(s8v a, s8v b, f4v c) {
    return mfma_k32(a, b, c, 0);
}

__device__ __forceinline__ unsigned short f2bf(float f) {
    union { float f; unsigned int i; } v; v.f = f;
    unsigned int r = v.i + 0x7FFFu + ((v.i >> 16) & 1u);
    return (unsigned short)(r >> 16);
}

// ---- prep: planes (3C,H,W) fp32 -> (3,H,W,C) bf16 ---------------------------
__global__ void prep_planes_k(const float* __restrict__ tp) {
    int o = blockIdx.x * 256 + threadIdx.x;   // 1572864 threads
    if (o >= 3 * HW_ * C_) return;
    int c  = o & 31;
    int xy = (o >> 5) & (HW_ - 1);
    int pl = o >> 19;
    g_planes[o] = f2bf(tp[(pl * C_ + c) * HW_ + xy]);
}

// ---- prep: weights/biases -> bf16; w2/b2 permuted [1,2,3,0], padded ---------
__global__ void prep_weights_k(const float* __restrict__ w0, const float* __restrict__ b0,
                               const float* __restrict__ w1, const float* __restrict__ b1,
                               const float* __restrict__ w2, const float* __restrict__ b2) {
    int i = blockIdx.x * 256 + threadIdx.x;   // 16384 threads
    if (i < 128 * 32)  g_w0[i] = f2bf(w0[i]);
    if (i < 128 * 128) g_w1[i] = f2bf(w1[i]);
    if (i < 16 * 128) {
        int n = i >> 7, k = i & 127;
        g_w2[i] = f2bf(n < 4 ? w2[((n + 1) & 3) * 128 + k] : 0.0f);
    }
    if (i < 128) { g_b0[i] = b0[i]; g_b1[i] = b1[i]; }
    if (i < 16)  g_b2p[i] = (i < 4) ? b2[(i + 1) & 3] : 0.0f;
}

// ---- bilinear sample: all 32 channels via 16B vector loads ------------------
__device__ __forceinline__ void sample_plane32(const unsigned short* __restrict__ pbase,
                                               float u, float v, float* facc) {
    float x = (u + 1.0f) * 63.5f;             // align_corners=True, W=H=128
    float y = (v + 1.0f) * 63.5f;
    float xf = floorf(x), yf = floorf(y);
    float wx = x - xf, wy = y - yf;
    int x0 = (int)xf, y0 = (int)yf;
#pragma unroll
    for (int dy = 0; dy < 2; ++dy) {
        int yi = y0 + dy;
        float wyv = dy ? wy : 1.0f - wy;
        bool vy = (yi >= 0) && (yi < 128);
        int yc = yi < 0 ? 0 : (yi > 127 ? 127 : yi);
#pragma unroll
        for (int dx = 0; dx < 2; ++dx) {
            int xi = x0 + dx;
            float wv = (dx ? wx : 1.0f - wx) * wyv;
            bool vx = (xi >= 0) && (xi < 128);
            int xc = xi < 0 ? 0 : (xi > 127 ? 127 : xi);
            wv = (vx && vy) ? wv : 0.0f;
            const u4v* cp = (const u4v*)(pbase + (yc * 128 + xc) * C_);
#pragma unroll
            for (int q = 0; q < 4; ++q) {
                u4v dw = cp[q];
#pragma unroll
                for (int jj = 0; jj < 4; ++jj) {
                    facc[q * 8 + 2 * jj]     += wv * __uint_as_float(dw[jj] << 16);
                    facc[q * 8 + 2 * jj + 1] += wv * __uint_as_float(dw[jj] & 0xFFFF0000u);
                }
            }
        }
    }
}

// ---- fused kernel -----------------------------------------------------------
__global__ __launch_bounds__(256) void fused_k(const float* __restrict__ coords,
                                               float* __restrict__ out) {
    // [w0: 8 blk*512][w1: 32 blk*512][S: 32KB, later overlaid by hb bufs]
    __shared__ __attribute__((aligned(16))) unsigned short smem[4096 + 16384 + 16384];
    unsigned short* w0l = smem;
    unsigned short* w1l = smem + 4096;
    unsigned short* S   = smem + 4096 + 16384;

    const int tid  = threadIdx.x;             // 0..255
    const int wave = tid >> 6;                // 0..3
    const int lane = tid & 63;
    const int l15  = lane & 15;
    const int quad = lane >> 4;
    const int ch8  = quad * 8;

    const int wg = blockIdx.x;                // 0..2047
    const int b  = wg >> 9;                   // batch
    const int nb = wg & 511;                  // 512-point block within batch
    const int n0 = nb << 9;

    // ---- stage weights into LDS, fragment-ready layout ----------------------
    // w0: block nt (0..7): [lane][8ch]; frag(nt) lane reads lane*16B. 512 chunks.
#pragma unroll
    for (int k = 0; k < 2; ++k) {
        const int cid = tid + k * 256;        // 0..511
        const int blk = cid >> 6, ls = cid & 63;
        s8v v = *(const s8v*)(g_w0 + (blk * 16 + (ls & 15)) * 32 + (ls >> 4) * 8);
        *(s8v*)(w0l + blk * 512 + ls * 8) = v;
    }
    // w1: block (kc*8+nt): [lane][8ch]. 2048 chunks.
#pragma unroll
    for (int k = 0; k < 8; ++k) {
        const int cid = tid + k * 256;        // 0..2047
        const int blk = cid >> 6, ls = cid & 63;
        const int kc = blk >> 3, ntj = blk & 7;
        s8v v = *(const s8v*)(g_w1 + (ntj * 16 + (ls & 15)) * 128 + kc * 32 + (ls >> 4) * 8);
        *(s8v*)(w1l + blk * 512 + ls * 8) = v;
    }

    // ---- phase A: sample 2 points/thread, all 32 channels -> S --------------
#pragma unroll 1
    for (int pt = 0; pt < 2; ++pt) {
        const int nl = tid + pt * 256;        // n_local 0..511
        const float* cp = coords + (size_t)(b * 262144 + n0 + nl) * 3;
        const float gx = cp[0], gy = cp[1], gz = cp[2];
        float facc[32];
#pragma unroll
        for (int c = 0; c < 32; ++c) facc[c] = 0.0f;
        sample_plane32(g_planes + 0 * (HW_ * C_), gx, gy, facc);  // feat_xy
        sample_plane32(g_planes + 2 * (HW_ * C_), gx, gz, facc);  // feat_xz
        sample_plane32(g_planes + 1 * (HW_ * C_), gy, gz, facc);  // feat_yz
#pragma unroll
        for (int c = 0; c < 32; ++c)
            S[c * 512 + nl] = f2bf(facc[c]);
    }
    __syncthreads();

    // ---- prefetch this wave's 8 A-fragments, then free S for hb overlay -----
    s8v afr[8];
#pragma unroll
    for (int i = 0; i < 8; ++i) {
        const int ci = wave * 8 + i;
        afr[i] = *(const s8v*)(S + ci * 512 + l15 * 32 + ch8);
    }
    __syncthreads();                          // all afr reads done; S dead

    // ---- small register state: w2 fragments + biases ------------------------
    s8v w2f[4];
#pragma unroll
    for (int kc = 0; kc < 4; ++kc)
        w2f[kc] = *(const s8v*)(g_w2 + l15 * 128 + kc * 32 + ch8);
    float bias0[8], bias1[8];
#pragma unroll
    for (int nt = 0; nt < 8; ++nt) {
        bias0[nt] = g_b0[nt * 16 + l15];
        bias1[nt] = g_b1[nt * 16 + l15];
    }
    const float bias2 = g_b2p[l15];

    unsigned short* hb = S + wave * (16 * HBS);   // per-wave private (8704<=16384)
    float* hbf = (float*)hb;

    // ---- phase B: 8 channel-tiles per wave ----------------------------------
#pragma unroll 1
    for (int i = 0; i < 8; ++i) {
        const int ci = wave * 8 + i;          // channel 0..31

        // layer 1: w0 fragment = sequential LDS read (base + lane*16B)
#pragma unroll
        for (int nt = 0; nt < 8; ++nt) {
            const s8v w0f = *(const s8v*)(w0l + nt * 512 + lane * 8);
            f4v bi;
            bi[0] = bias0[nt]; bi[1] = bias0[nt]; bi[2] = bias0[nt]; bi[3] = bias0[nt];
            f4v c1 = MFMA(afr[i], w0f, bi);
#pragma unroll
            for (int r = 0; r < 4; ++r) {
                float v = c1[r];
                hb[(quad * 4 + r) * HBS + nt * 16 + l15] = f2bf(v > 0.0f ? v : 0.0f);
            }
        }
        __builtin_amdgcn_s_waitcnt(0);
        s8v a2[4];
#pragma unroll
        for (int kc = 0; kc < 4; ++kc)
            a2[kc] = *(const s8v*)(hb + l15 * HBS + kc * 32 + ch8);

        // layer 2 in two nt-halves; w1 fragments = sequential LDS reads
#pragma unroll
        for (int half = 0; half < 2; ++half) {
            f4v d[4];
#pragma unroll
            for (int j = 0; j < 4; ++j) {
                float bv = bias1[half * 4 + j];
                d[j][0] = bv; d[j][1] = bv; d[j][2] = bv; d[j][3] = bv;
            }
#pragma unroll
            for (int kc = 0; kc < 4; ++kc) {
#pragma unroll
                for (int j = 0; j < 4; ++j) {
                    const s8v w1f = *(const s8v*)(w1l +
                        (kc * 8 + half * 4 + j) * 512 + lane * 8);
                    d[j] = MFMA(a2[kc], w1f, d[j]);
                }
            }
#pragma unroll
            for (int j = 0; j < 4; ++j)
#pragma unroll
                for (int r = 0; r < 4; ++r) {
                    float v = d[j][r];
                    hb[(quad * 4 + r) * HBS + (half * 4 + j) * 16 + l15] =
                        f2bf(v > 0.0f ? v : 0.0f);
                }
        }
        __builtin_amdgcn_s_waitcnt(0);
#pragma unroll
        for (int kc = 0; kc < 4; ++kc)        // reuse a2 as the layer-3 A frag
            a2[kc] = *(const s8v*)(hb + l15 * HBS + kc * 32 + ch8);

        // layer 3 -> relu
        f4v o;
        o[0] = bias2; o[1] = bias2; o[2] = bias2; o[3] = bias2;
#pragma unroll
        for (int kc = 0; kc < 4; ++kc)
            o = MFMA(a2[kc], w2f[kc], o);

        // transpose 16x4 through LDS -> one coalesced 256B store per tile
        if (l15 < 4) {
#pragma unroll
            for (int r = 0; r < 4; ++r) {
                float v = o[r];
                hbf[(quad * 4 + r) * 4 + l15] = v > 0.0f ? v : 0.0f;
            }
        }
        __builtin_amdgcn_s_waitcnt(0);
        const int t = b * 16384 + ci * 512 + nb;   // global tile index
        if (lane < 16) {
            f4v row = *(const f4v*)(hbf + lane * 4);
            *(f4v*)(out + (size_t)(t * 16 + lane) * 4) = row;
        }
        __builtin_amdgcn_s_waitcnt(0);        // hbf reads done before next tile
    }
}

extern "C" void kernel_launch(void* const* d_in, const int* in_sizes, int n_in,
                              void* d_out, int out_size, void* d_ws, size_t ws_size,
                              hipStream_t stream) {
    const float* coords = (const float*)d_in[0];
    const float* tp = (const float*)d_in[1];
    const float* w0 = (const float*)d_in[2];
    const float* b0 = (const float*)d_in[3];
    const float* w1 = (const float*)d_in[4];
    const float* b1 = (const float*)d_in[5];
    const float* w2 = (const float*)d_in[6];
    const float* b2 = (const float*)d_in[7];
    float* out = (float*)d_out;               // FP32 output

    prep_planes_k<<<6144, 256, 0, stream>>>(tp);
    prep_weights_k<<<64, 256, 0, stream>>>(w0, b0, w1, b1, w2, b2);
    fused_k<<<2048, 256, 0, stream>>>(coords, out);
}

// Round 15
// 322.126 us; speedup vs baseline: 1.3464x; 1.0014x over previous
//
#include <hip/hip_runtime.h>
#include <hip/hip_bf16.h>

// Fused triplane sample + reshape-semantics MLP (32->128->128->4, ReLU),
// FP32 out, perm [1,2,3,0] baked into w2/b2.
// r14 structure (weights in LDS fragment-ready, 2 blocks/CU) with ONE change:
// phase-B waits are lgkm-only (0xC07F = vmcnt63/exp7/lgkm0) instead of full
// waitcnt(0) -- the full drains were serializing each tile against the
// previous tile's global store retirement (~500cyc x4 per tile).

#define C_ 32
#define HW_ (128 * 128)
#define HBS 136               /* per-wave transpose buf row stride (bf16) */
#define WAIT_LGKM() __builtin_amdgcn_s_waitcnt(0xC07F)  /* lgkmcnt(0) only */

typedef short s8v __attribute__((ext_vector_type(8)));
typedef float f4v __attribute__((ext_vector_type(4)));
typedef unsigned int u4v __attribute__((ext_vector_type(4)));

__device__ __attribute__((aligned(64))) unsigned short g_planes[3 * HW_ * C_]; // (3,H,W,C) bf16
__device__ __attribute__((aligned(16))) unsigned short g_w0[128 * 32];
__device__ __attribute__((aligned(16))) unsigned short g_w1[128 * 128];
__device__ __attribute__((aligned(16))) unsigned short g_w2[16 * 128];  // perm-baked, padded
__device__ float g_b0[128];
__device__ float g_b1[128];
__device__ float g_b2p[16];

template <typename TO, typename FROM>
static __device__ __forceinline__ TO bitc(FROM f) {
    union { FROM a; TO b; } u; u.a = f; return u.b;
}

// MFMA operand-type shim (v8i16 vs v8bf16 builtin signature) -- proven.
template <typename V>
static __device__ __forceinline__ auto mfma_k32(V a, V b, f4v c, int)
    -> decltype(__builtin_amdgcn_mfma_f32_16x16x32_bf16(a, b, c, 0, 0, 0)) {
    return __builtin_amdgcn_mfma_f32_16x16x32_bf16(a, b, c, 0, 0, 0);
}
template <typename V>
static __device__ __forceinline__ f4v mfma_k32(V a, V b, f4v c, long) {
    typedef __bf16 b8v __attribute__((ext_vector_type(8)));
    return __builtin_amdgcn_mfma_f32_16x16x32_bf16(bitc<b8v>(a), bitc<b8v>(b), c, 0, 0, 0);
}
static __device__ __forceinline__ f4v MFMA(s8v a, s8v b, f4v c) {
    return mfma_k32(a, b, c, 0);
}

__device__ __forceinline__ unsigned short f2bf(float f) {
    union { float f; unsigned int i; } v; v.f = f;
    unsigned int r = v.i + 0x7FFFu + ((v.i >> 16) & 1u);
    return (unsigned short)(r >> 16);
}

// ---- prep: planes (3C,H,W) fp32 -> (3,H,W,C) bf16 ---------------------------
__global__ void prep_planes_k(const float* __restrict__ tp) {
    int o = blockIdx.x * 256 + threadIdx.x;   // 1572864 threads
    if (o >= 3 * HW_ * C_) return;
    int c  = o & 31;
    int xy = (o >> 5) & (HW_ - 1);
    int pl = o >> 19;
    g_planes[o] = f2bf(tp[(pl * C_ + c) * HW_ + xy]);
}

// ---- prep: weights/biases -> bf16; w2/b2 permuted [1,2,3,0], padded ---------
__global__ void prep_weights_k(const float* __restrict__ w0, const float* __restrict__ b0,
                               const float* __restrict__ w1, const float* __restrict__ b1,
                               const float* __restrict__ w2, const float* __restrict__ b2) {
    int i = blockIdx.x * 256 + threadIdx.x;   // 16384 threads
    if (i < 128 * 32)  g_w0[i] = f2bf(w0[i]);
    if (i < 128 * 128) g_w1[i] = f2bf(w1[i]);
    if (i < 16 * 128) {
        int n = i >> 7, k = i & 127;
        g_w2[i] = f2bf(n < 4 ? w2[((n + 1) & 3) * 128 + k] : 0.0f);
    }
    if (i < 128) { g_b0[i] = b0[i]; g_b1[i] = b1[i]; }
    if (i < 16)  g_b2p[i] = (i < 4) ? b2[(i + 1) & 3] : 0.0f;
}

// ---- bilinear sample: all 32 channels via 16B vector loads ------------------
__device__ __forceinline__ void sample_plane32(const unsigned short* __restrict__ pbase,
                                               float u, float v, float* facc) {
    float x = (u + 1.0f) * 63.5f;             // align_corners=True, W=H=128
    float y = (v + 1.0f) * 63.5f;
    float xf = floorf(x), yf = floorf(y);
    float wx = x - xf, wy = y - yf;
    int x0 = (int)xf, y0 = (int)yf;
#pragma unroll
    for (int dy = 0; dy < 2; ++dy) {
        int yi = y0 + dy;
        float wyv = dy ? wy : 1.0f - wy;
        bool vy = (yi >= 0) && (yi < 128);
        int yc = yi < 0 ? 0 : (yi > 127 ? 127 : yi);
#pragma unroll
        for (int dx = 0; dx < 2; ++dx) {
            int xi = x0 + dx;
            float wv = (dx ? wx : 1.0f - wx) * wyv;
            bool vx = (xi >= 0) && (xi < 128);
            int xc = xi < 0 ? 0 : (xi > 127 ? 127 : xi);
            wv = (vx && vy) ? wv : 0.0f;
            const u4v* cp = (const u4v*)(pbase + (yc * 128 + xc) * C_);
#pragma unroll
            for (int q = 0; q < 4; ++q) {
                u4v dw = cp[q];
#pragma unroll
                for (int jj = 0; jj < 4; ++jj) {
                    facc[q * 8 + 2 * jj]     += wv * __uint_as_float(dw[jj] << 16);
                    facc[q * 8 + 2 * jj + 1] += wv * __uint_as_float(dw[jj] & 0xFFFF0000u);
                }
            }
        }
    }
}

// ---- fused kernel -----------------------------------------------------------
__global__ __launch_bounds__(256) void fused_k(const float* __restrict__ coords,
                                               float* __restrict__ out) {
    // [w0: 8 blk*512][w1: 32 blk*512][S: 32KB, later overlaid by hb bufs]
    __shared__ __attribute__((aligned(16))) unsigned short smem[4096 + 16384 + 16384];
    unsigned short* w0l = smem;
    unsigned short* w1l = smem + 4096;
    unsigned short* S   = smem + 4096 + 16384;

    const int tid  = threadIdx.x;             // 0..255
    const int wave = tid >> 6;                // 0..3
    const int lane = tid & 63;
    const int l15  = lane & 15;
    const int quad = lane >> 4;
    const int ch8  = quad * 8;

    const int wg = blockIdx.x;                // 0..2047
    const int b  = wg >> 9;                   // batch
    const int nb = wg & 511;                  // 512-point block within batch
    const int n0 = nb << 9;

    // ---- stage weights into LDS, fragment-ready layout ----------------------
#pragma unroll
    for (int k = 0; k < 2; ++k) {
        const int cid = tid + k * 256;        // 0..511
        const int blk = cid >> 6, ls = cid & 63;
        s8v v = *(const s8v*)(g_w0 + (blk * 16 + (ls & 15)) * 32 + (ls >> 4) * 8);
        *(s8v*)(w0l + blk * 512 + ls * 8) = v;
    }
#pragma unroll
    for (int k = 0; k < 8; ++k) {
        const int cid = tid + k * 256;        // 0..2047
        const int blk = cid >> 6, ls = cid & 63;
        const int kc = blk >> 3, ntj = blk & 7;
        s8v v = *(const s8v*)(g_w1 + (ntj * 16 + (ls & 15)) * 128 + kc * 32 + (ls >> 4) * 8);
        *(s8v*)(w1l + blk * 512 + ls * 8) = v;
    }

    // ---- phase A: sample 2 points/thread, all 32 channels -> S --------------
#pragma unroll 1
    for (int pt = 0; pt < 2; ++pt) {
        const int nl = tid + pt * 256;        // n_local 0..511
        const float* cp = coords + (size_t)(b * 262144 + n0 + nl) * 3;
        const float gx = cp[0], gy = cp[1], gz = cp[2];
        float facc[32];
#pragma unroll
        for (int c = 0; c < 32; ++c) facc[c] = 0.0f;
        sample_plane32(g_planes + 0 * (HW_ * C_), gx, gy, facc);  // feat_xy
        sample_plane32(g_planes + 2 * (HW_ * C_), gx, gz, facc);  // feat_xz
        sample_plane32(g_planes + 1 * (HW_ * C_), gy, gz, facc);  // feat_yz
#pragma unroll
        for (int c = 0; c < 32; ++c)
            S[c * 512 + nl] = f2bf(facc[c]);
    }
    __syncthreads();

    // ---- prefetch this wave's 8 A-fragments, then free S for hb overlay -----
    s8v afr[8];
#pragma unroll
    for (int i = 0; i < 8; ++i) {
        const int ci = wave * 8 + i;
        afr[i] = *(const s8v*)(S + ci * 512 + l15 * 32 + ch8);
    }
    __syncthreads();                          // all afr reads done; S dead

    // ---- small register state: w2 fragments + biases ------------------------
    s8v w2f[4];
#pragma unroll
    for (int kc = 0; kc < 4; ++kc)
        w2f[kc] = *(const s8v*)(g_w2 + l15 * 128 + kc * 32 + ch8);
    float bias0[8], bias1[8];
#pragma unroll
    for (int nt = 0; nt < 8; ++nt) {
        bias0[nt] = g_b0[nt * 16 + l15];
        bias1[nt] = g_b1[nt * 16 + l15];
    }
    const float bias2 = g_b2p[l15];

    unsigned short* hb = S + wave * (16 * HBS);   // per-wave private (8704<=16384)
    float* hbf = (float*)hb;

    // ---- phase B: 8 channel-tiles per wave ----------------------------------
#pragma unroll 1
    for (int i = 0; i < 8; ++i) {
        const int ci = wave * 8 + i;          // channel 0..31

        // layer 1: w0 fragment = sequential LDS read (base + lane*16B)
#pragma unroll
        for (int nt = 0; nt < 8; ++nt) {
            const s8v w0f = *(const s8v*)(w0l + nt * 512 + lane * 8);
            f4v bi;
            bi[0] = bias0[nt]; bi[1] = bias0[nt]; bi[2] = bias0[nt]; bi[3] = bias0[nt];
            f4v c1 = MFMA(afr[i], w0f, bi);
#pragma unroll
            for (int r = 0; r < 4; ++r) {
                float v = c1[r];
                hb[(quad * 4 + r) * HBS + nt * 16 + l15] = f2bf(v > 0.0f ? v : 0.0f);
            }
        }
        WAIT_LGKM();
        s8v a2[4];
#pragma unroll
        for (int kc = 0; kc < 4; ++kc)
            a2[kc] = *(const s8v*)(hb + l15 * HBS + kc * 32 + ch8);

        // layer 2 in two nt-halves; w1 fragments = sequential LDS reads
#pragma unroll
        for (int half = 0; half < 2; ++half) {
            f4v d[4];
#pragma unroll
            for (int j = 0; j < 4; ++j) {
                float bv = bias1[half * 4 + j];
                d[j][0] = bv; d[j][1] = bv; d[j][2] = bv; d[j][3] = bv;
            }
#pragma unroll
            for (int kc = 0; kc < 4; ++kc) {
#pragma unroll
                for (int j = 0; j < 4; ++j) {
                    const s8v w1f = *(const s8v*)(w1l +
                        (kc * 8 + half * 4 + j) * 512 + lane * 8);
                    d[j] = MFMA(a2[kc], w1f, d[j]);
                }
            }
#pragma unroll
            for (int j = 0; j < 4; ++j)
#pragma unroll
                for (int r = 0; r < 4; ++r) {
                    float v = d[j][r];
                    hb[(quad * 4 + r) * HBS + (half * 4 + j) * 16 + l15] =
                        f2bf(v > 0.0f ? v : 0.0f);
                }
        }
        WAIT_LGKM();
#pragma unroll
        for (int kc = 0; kc < 4; ++kc)        // reuse a2 as the layer-3 A frag
            a2[kc] = *(const s8v*)(hb + l15 * HBS + kc * 32 + ch8);

        // layer 3 -> relu
        f4v o;
        o[0] = bias2; o[1] = bias2; o[2] = bias2; o[3] = bias2;
#pragma unroll
        for (int kc = 0; kc < 4; ++kc)
            o = MFMA(a2[kc], w2f[kc], o);

        // transpose 16x4 through LDS -> one coalesced 256B store per tile
        if (l15 < 4) {
#pragma unroll
            for (int r = 0; r < 4; ++r) {
                float v = o[r];
                hbf[(quad * 4 + r) * 4 + l15] = v > 0.0f ? v : 0.0f;
            }
        }
        WAIT_LGKM();
        const int t = b * 16384 + ci * 512 + nb;   // global tile index
        if (lane < 16) {
            f4v row = *(const f4v*)(hbf + lane * 4);
            *(f4v*)(out + (size_t)(t * 16 + lane) * 4) = row;
        }
        WAIT_LGKM();                          // hbf reads done before next tile
    }
}

extern "C" void kernel_launch(void* const* d_in, const int* in_sizes, int n_in,
                              void* d_out, int out_size, void* d_ws, size_t ws_size,
                              hipStream_t stream) {
    const float* coords = (const float*)d_in[0];
    const float* tp = (const float*)d_in[1];
    const float* w0 = (const float*)d_in[2];
    const float* b0 = (const float*)d_in[3];
    const float* w1 = (const float*)d_in[4];
    const float* b1 = (const float*)d_in[5];
    const float* w2 = (const float*)d_in[6];
    const float* b2 = (const float*)d_in[7];
    float* out = (float*)d_out;               // FP32 output

    prep_planes_k<<<6144, 256, 0, stream>>>(tp);
    prep_weights_k<<<64, 256, 0, stream>>>(w0, b0, w1, b1, w2, b2);
    fused_k<<<2048, 256, 0, stream>>>(coords, out);
}